// Round 3
// baseline (604.644 us; speedup 1.0000x reference)
//
#include <hip/hip_runtime.h>
#include <hip/hip_bf16.h>

// 2-NN: out[q] = sum of 2 smallest ||q - t||^2 over 200000 train points.
// d2 = q_sq + t_sq - 2*q.t ; top-2 depends only on s = t_sq - 2*q.t.
// Pipeline: (1) convert train/test fp32->bf16 + exact fp32 row norms,
// (2) MFMA GEMM (16x16x32 bf16); train tile staged via global_load_lds
//     (linear LDS dest, PRE-SWIZZLED global source; XOR-swizzled ds_read),
//     double-buffered, 1 barrier/iter, fused per-lane top-2 of s,
// (3) shuffle-merge + per-chunk partials, (4) reduce partials.

typedef short bf16x8 __attribute__((ext_vector_type(8)));   // 8 bf16 = 4 VGPRs
typedef float f32x4 __attribute__((ext_vector_type(4)));

#define N_TRAIN 200000
#define M_QUERY 2048
#define DIMS 128
#define TB 32                     // train points per pipeline tile (8 KB)

__device__ __forceinline__ unsigned int bf_bits(float f) {
  unsigned int u = __float_as_uint(f);
  return (u + 0x7FFFu + ((u >> 16) & 1u)) >> 16;
}

// 8 lanes per row; each lane handles 16 contiguous floats (64B) -> coalesced.
__global__ __launch_bounds__(256) void convert_kernel(
    const float* __restrict__ src, unsigned short* __restrict__ dst,
    float* __restrict__ sq, int nrows) {
  int gtid = blockIdx.x * 256 + threadIdx.x;
  int row = gtid >> 3, sub = gtid & 7;
  if (row >= nrows) return;
  const float4* s4 = reinterpret_cast<const float4*>(src + (size_t)row * DIMS + sub * 16);
  unsigned int pk[8];
  float acc = 0.f;
#pragma unroll
  for (int i = 0; i < 4; ++i) {
    float4 v = s4[i];
    acc += v.x * v.x + v.y * v.y + v.z * v.z + v.w * v.w;
    pk[i * 2 + 0] = bf_bits(v.x) | (bf_bits(v.y) << 16);
    pk[i * 2 + 1] = bf_bits(v.z) | (bf_bits(v.w) << 16);
  }
  uint4* d4 = reinterpret_cast<uint4*>(dst + (size_t)row * DIMS + sub * 16);
  d4[0] = make_uint4(pk[0], pk[1], pk[2], pk[3]);
  d4[1] = make_uint4(pk[4], pk[5], pk[6], pk[7]);
  acc += __shfl_xor(acc, 1);
  acc += __shfl_xor(acc, 2);
  acc += __shfl_xor(acc, 4);
  if (sub == 0) sq[row] = acc;
}

// Main: grid (8 qblocks fast, nchunk slow) so the 8 blocks sharing a chunk
// dispatch consecutively across the 8 XCDs (train streams L3 once).
// Block = 4 waves; wave owns 64 queries. Train tile double-buffered in LDS.
template <int PPC>
__global__ __launch_bounds__(256, 5) void knn_main(
    const unsigned short* __restrict__ tb, const unsigned short* __restrict__ qb16,
    const float* __restrict__ tsq, float* __restrict__ partials) {
  constexpr int ITERS = PPC / TB;
  const int chunk = blockIdx.y;
  const int qblock = blockIdx.x * 256;
  const int tid = threadIdx.x;
  const int w = tid >> 6, l = tid & 63;
  const int lo = l & 15, hi = l >> 4;
  const int qw = qblock + w * 64;

  __shared__ char smem[2 * 8192];           // 2 x 8 KB train tiles (linear layout)
  __shared__ float tsq_s[PPC];              // chunk's t_sq

  // A-fragments: lane reads Q[qw + t*16 + lo][kf*32 + hi*8 .. +8]
  bf16x8 a[4][4];
#pragma unroll
  for (int t = 0; t < 4; ++t)
#pragma unroll
    for (int kf = 0; kf < 4; ++kf)
      a[t][kf] = *reinterpret_cast<const bf16x8*>(
          qb16 + (size_t)(qw + t * 16 + lo) * DIMS + kf * 32 + hi * 8);

  // global_load_lds: LDS dest linear (wave base + lane*16); global source
  // pre-swizzled so LDS[(row, blk)] = global(row, blk ^ (row&7)).
  // Thread covers LDS bytes tid*16 (row srow=tid>>4) and tid*16+4096 (row+16,
  // same row&7 -> same swizzle, source is simply +4096).
  const int srow = tid >> 4, sblk = tid & 15;
  const char* gsrc = reinterpret_cast<const char*>(tb) +
                     (size_t)chunk * PPC * 256 + srow * 256 + ((sblk ^ (srow & 7)) << 4);
  char* lbase = smem + w * 1024;            // wave-uniform LDS base (lane adds l*16)

  // ds_read offsets (unchanged from verified r2 layout):
  // B-frag for point p = 16*half + lo, block kb = kf*4+hi:
  // addr = p*256 + ((kb ^ (p&7)) << 4); +4096 for the upper half.
  int roff[4];
#pragma unroll
  for (int kf = 0; kf < 4; ++kf)
    roff[kf] = lo * 256 + ((((kf << 2) + hi) ^ (lo & 7)) << 4);

  const float INF = __builtin_inff();
  float best1[4][4], best2[4][4];
#pragma unroll
  for (int t = 0; t < 4; ++t)
#pragma unroll
    for (int r = 0; r < 4; ++r) { best1[t][r] = INF; best2[t][r] = INF; }

  // prologue: stage tile 0 into buffer 0 + t_sq chunk into LDS
  __builtin_amdgcn_global_load_lds(
      (const __attribute__((address_space(1))) void*)gsrc,
      (__attribute__((address_space(3))) void*)lbase, 16, 0, 0);
  __builtin_amdgcn_global_load_lds(
      (const __attribute__((address_space(1))) void*)(gsrc + 4096),
      (__attribute__((address_space(3))) void*)(lbase + 4096), 16, 0, 0);
  gsrc += TB * 256;
  for (int i = tid; i < PPC; i += 256) tsq_s[i] = tsq[chunk * PPC + i];
  __syncthreads();

  int cur = 0;
  for (int it = 0; it < ITERS; ++it) {
    if (it + 1 < ITERS) {  // async-stage next tile into the other buffer
      char* nb = lbase + ((cur ^ 1) << 13);
      __builtin_amdgcn_global_load_lds(
          (const __attribute__((address_space(1))) void*)gsrc,
          (__attribute__((address_space(3))) void*)nb, 16, 0, 0);
      __builtin_amdgcn_global_load_lds(
          (const __attribute__((address_space(1))) void*)(gsrc + 4096),
          (__attribute__((address_space(3))) void*)(nb + 4096), 16, 0, 0);
      gsrc += TB * 256;
    }
    float tv0 = tsq_s[it * TB + lo];
    float tv1 = tsq_s[it * TB + 16 + lo];

    const char* buf = smem + (cur << 13);
    bf16x8 f0[4], f1[4];
#pragma unroll
    for (int kf = 0; kf < 4; ++kf) {
      f0[kf] = *reinterpret_cast<const bf16x8*>(buf + roff[kf]);
      f1[kf] = *reinterpret_cast<const bf16x8*>(buf + roff[kf] + 4096);
    }

    const f32x4 z = {0.f, 0.f, 0.f, 0.f};
#pragma unroll
    for (int t = 0; t < 4; ++t) {
      f32x4 acc0 = __builtin_amdgcn_mfma_f32_16x16x32_bf16(a[t][0], f0[0], z, 0, 0, 0);
      f32x4 acc1 = __builtin_amdgcn_mfma_f32_16x16x32_bf16(a[t][0], f1[0], z, 0, 0, 0);
#pragma unroll
      for (int kf = 1; kf < 4; ++kf) {
        acc0 = __builtin_amdgcn_mfma_f32_16x16x32_bf16(a[t][kf], f0[kf], acc0, 0, 0, 0);
        acc1 = __builtin_amdgcn_mfma_f32_16x16x32_bf16(a[t][kf], f1[kf], acc1, 0, 0, 0);
      }
#pragma unroll
      for (int r = 0; r < 4; ++r) {
        float s0 = fmaf(-2.f, acc0[r], tv0);
        float n1 = fminf(best1[t][r], s0);
        float n2 = __builtin_amdgcn_fmed3f(best1[t][r], best2[t][r], s0);
        best1[t][r] = n1; best2[t][r] = n2;
        float s1 = fmaf(-2.f, acc1[r], tv1);
        n1 = fminf(best1[t][r], s1);
        n2 = __builtin_amdgcn_fmed3f(best1[t][r], best2[t][r], s1);
        best1[t][r] = n1; best2[t][r] = n2;
      }
    }
    __syncthreads();   // drains vmcnt (gll) + lgkmcnt; next tile ready, cur-buf reads done
    cur ^= 1;
  }

  // merge top-2 across the 16 lanes (columns) sharing each query
#pragma unroll
  for (int t = 0; t < 4; ++t)
#pragma unroll
    for (int r = 0; r < 4; ++r) {
      float v1 = best1[t][r], v2 = best2[t][r];
#pragma unroll
      for (int m = 1; m < 16; m <<= 1) {
        float o1 = __shfl_xor(v1, m);
        float o2 = __shfl_xor(v2, m);
        float n1 = fminf(v1, o1);
        float n2 = fminf(fmaxf(v1, o1), fminf(v2, o2));
        v1 = n1;
        v2 = n2;
      }
      best1[t][r] = v1;
      best2[t][r] = v2;
    }
  if (lo == 0) {
#pragma unroll
    for (int t = 0; t < 4; ++t)
#pragma unroll
      for (int r = 0; r < 4; ++r) {
        int q = qw + t * 16 + hi * 4 + r;
        float* p = partials + ((size_t)chunk * M_QUERY + q) * 2;
        p[0] = best1[t][r];
        p[1] = best2[t][r];
      }
  }
}

__global__ __launch_bounds__(256) void knn_reduce(
    const float* __restrict__ partials, const float* __restrict__ qsq,
    float* __restrict__ out, int nchunk) {
  int q = blockIdx.x * 256 + threadIdx.x;
  if (q >= M_QUERY) return;
  const float INF = __builtin_inff();
  float b1 = INF, b2 = INF;
  for (int c = 0; c < nchunk; ++c) {
    const float* p = partials + ((size_t)c * M_QUERY + q) * 2;
    float v = p[0];
    float n1 = fminf(b1, v);
    float n2 = __builtin_amdgcn_fmed3f(b1, b2, v);
    b1 = n1; b2 = n2;
    v = p[1];
    n1 = fminf(b1, v);
    n2 = __builtin_amdgcn_fmed3f(b1, b2, v);
    b1 = n1; b2 = n2;
  }
  out[q] = 2.f * qsq[q] + b1 + b2;
}

extern "C" void kernel_launch(void* const* d_in, const int* in_sizes, int n_in,
                              void* d_out, int out_size, void* d_ws, size_t ws_size,
                              hipStream_t stream) {
  const float* train = (const float*)d_in[0];  // 200000 x 128 f32
  const float* test  = (const float*)d_in[1];  // 2048 x 128 f32
  float* out = (float*)d_out;                  // 2048 f32
  char* ws = (char*)d_ws;

  size_t off_tb  = 0;                                      // train bf16: 51,200,000 B
  size_t off_qb  = off_tb  + (size_t)N_TRAIN * DIMS * 2;   // query bf16
  size_t off_tsq = off_qb  + (size_t)M_QUERY * DIMS * 2;   // t_sq
  size_t off_qsq = off_tsq + (size_t)N_TRAIN * 4;          // q_sq
  size_t off_pt  = off_qsq + (size_t)M_QUERY * 4;          // partials
  size_t need250 = off_pt + (size_t)250 * M_QUERY * 2 * 4;
  size_t need125 = off_pt + (size_t)125 * M_QUERY * 2 * 4;
  if (ws_size < need125) return;
  const bool use250 = (ws_size >= need250);

  unsigned short* tbp = (unsigned short*)(ws + off_tb);
  unsigned short* qb  = (unsigned short*)(ws + off_qb);
  float* tsq = (float*)(ws + off_tsq);
  float* qsq = (float*)(ws + off_qsq);
  float* part = (float*)(ws + off_pt);

  hipLaunchKernelGGL(convert_kernel, dim3((N_TRAIN * 8) / 256), dim3(256), 0, stream,
                     train, tbp, tsq, N_TRAIN);
  hipLaunchKernelGGL(convert_kernel, dim3((M_QUERY * 8) / 256), dim3(256), 0, stream,
                     test, qb, qsq, M_QUERY);
  if (use250) {
    hipLaunchKernelGGL(knn_main<800>, dim3(8, 250), dim3(256), 0, stream,
                       tbp, qb, tsq, part);
    hipLaunchKernelGGL(knn_reduce, dim3(M_QUERY / 256), dim3(256), 0, stream,
                       part, qsq, out, 250);
  } else {
    hipLaunchKernelGGL(knn_main<1600>, dim3(8, 125), dim3(256), 0, stream,
                       tbp, qb, tsq, part);
    hipLaunchKernelGGL(knn_reduce, dim3(M_QUERY / 256), dim3(256), 0, stream,
                       part, qsq, out, 125);
  }
}

// Round 4
// 230.064 us; speedup vs baseline: 2.6282x; 2.6282x over previous
//
#include <hip/hip_runtime.h>
#include <hip/hip_bf16.h>

// 2-NN: out[q] = sum of 2 smallest ||q - t||^2 over 200000 train points.
// d2 = q_sq + t_sq - 2*q.t ; top-2 depends only on s = t_sq - 2*q.t.
// Pipeline: (1) convert train/test fp32->bf16 + exact fp32 row norms,
// (2) MFMA GEMM (16x16x32 bf16); train tile staged via global_load_lds
//     (linear LDS dest, PRE-SWIZZLED global source; XOR-swizzled ds_read),
//     double-buffered, 1 barrier/iter, fused per-lane top-2 of s,
// (3) shuffle-merge + per-chunk partials, (4) reduce partials.
// NOTE: no waves-per-EU cap in __launch_bounds__ — r3's (256,5) forced
// VGPR 92->48 and spilled a-frags/best to scratch (FETCH x8, 4x slower).

typedef short bf16x8 __attribute__((ext_vector_type(8)));   // 8 bf16 = 4 VGPRs
typedef float f32x4 __attribute__((ext_vector_type(4)));

#define N_TRAIN 200000
#define M_QUERY 2048
#define DIMS 128
#define TB 32                     // train points per pipeline tile (8 KB)

__device__ __forceinline__ unsigned int bf_bits(float f) {
  unsigned int u = __float_as_uint(f);
  return (u + 0x7FFFu + ((u >> 16) & 1u)) >> 16;
}

// 8 lanes per row; each lane handles 16 contiguous floats (64B) -> coalesced.
__global__ __launch_bounds__(256) void convert_kernel(
    const float* __restrict__ src, unsigned short* __restrict__ dst,
    float* __restrict__ sq, int nrows) {
  int gtid = blockIdx.x * 256 + threadIdx.x;
  int row = gtid >> 3, sub = gtid & 7;
  if (row >= nrows) return;
  const float4* s4 = reinterpret_cast<const float4*>(src + (size_t)row * DIMS + sub * 16);
  unsigned int pk[8];
  float acc = 0.f;
#pragma unroll
  for (int i = 0; i < 4; ++i) {
    float4 v = s4[i];
    acc += v.x * v.x + v.y * v.y + v.z * v.z + v.w * v.w;
    pk[i * 2 + 0] = bf_bits(v.x) | (bf_bits(v.y) << 16);
    pk[i * 2 + 1] = bf_bits(v.z) | (bf_bits(v.w) << 16);
  }
  uint4* d4 = reinterpret_cast<uint4*>(dst + (size_t)row * DIMS + sub * 16);
  d4[0] = make_uint4(pk[0], pk[1], pk[2], pk[3]);
  d4[1] = make_uint4(pk[4], pk[5], pk[6], pk[7]);
  acc += __shfl_xor(acc, 1);
  acc += __shfl_xor(acc, 2);
  acc += __shfl_xor(acc, 4);
  if (sub == 0) sq[row] = acc;
}

// Main: grid (8 qblocks fast, nchunk slow) so the 8 blocks sharing a chunk
// dispatch consecutively across the 8 XCDs (train streams L3 once).
// Block = 4 waves; wave owns 64 queries. Train tile double-buffered in LDS.
template <int PPC>
__global__ __launch_bounds__(256) void knn_main(
    const unsigned short* __restrict__ tb, const unsigned short* __restrict__ qb16,
    const float* __restrict__ tsq, float* __restrict__ partials) {
  constexpr int ITERS = PPC / TB;
  const int chunk = blockIdx.y;
  const int qblock = blockIdx.x * 256;
  const int tid = threadIdx.x;
  const int w = tid >> 6, l = tid & 63;
  const int lo = l & 15, hi = l >> 4;
  const int qw = qblock + w * 64;

  __shared__ char smem[2 * 8192];           // 2 x 8 KB train tiles (linear layout)
  __shared__ float tsq_s[PPC];              // chunk's t_sq

  // A-fragments: lane reads Q[qw + t*16 + lo][kf*32 + hi*8 .. +8]
  bf16x8 a[4][4];
#pragma unroll
  for (int t = 0; t < 4; ++t)
#pragma unroll
    for (int kf = 0; kf < 4; ++kf)
      a[t][kf] = *reinterpret_cast<const bf16x8*>(
          qb16 + (size_t)(qw + t * 16 + lo) * DIMS + kf * 32 + hi * 8);

  // global_load_lds: LDS dest linear (wave base + lane*16); global source
  // pre-swizzled so LDS[(row, blk)] = global(row, blk ^ (row&7)).
  const int srow = tid >> 4, sblk = tid & 15;
  const char* gsrc = reinterpret_cast<const char*>(tb) +
                     (size_t)chunk * PPC * 256 + srow * 256 + ((sblk ^ (srow & 7)) << 4);
  char* lbase = smem + w * 1024;            // wave-uniform LDS base (lane adds l*16)

  // ds_read offsets: B-frag for point p = 16*half + lo, block kb = kf*4+hi:
  // addr = p*256 + ((kb ^ (p&7)) << 4); +4096 for the upper half.
  int roff[4];
#pragma unroll
  for (int kf = 0; kf < 4; ++kf)
    roff[kf] = lo * 256 + ((((kf << 2) + hi) ^ (lo & 7)) << 4);

  const float INF = __builtin_inff();
  float best1[4][4], best2[4][4];
#pragma unroll
  for (int t = 0; t < 4; ++t)
#pragma unroll
    for (int r = 0; r < 4; ++r) { best1[t][r] = INF; best2[t][r] = INF; }

  // prologue: stage tile 0 into buffer 0 + t_sq chunk into LDS
  __builtin_amdgcn_global_load_lds(
      (const __attribute__((address_space(1))) void*)gsrc,
      (__attribute__((address_space(3))) void*)lbase, 16, 0, 0);
  __builtin_amdgcn_global_load_lds(
      (const __attribute__((address_space(1))) void*)(gsrc + 4096),
      (__attribute__((address_space(3))) void*)(lbase + 4096), 16, 0, 0);
  gsrc += TB * 256;
  for (int i = tid; i < PPC; i += 256) tsq_s[i] = tsq[chunk * PPC + i];
  __syncthreads();

  int cur = 0;
  for (int it = 0; it < ITERS; ++it) {
    if (it + 1 < ITERS) {  // async-stage next tile into the other buffer
      char* nb = lbase + ((cur ^ 1) << 13);
      __builtin_amdgcn_global_load_lds(
          (const __attribute__((address_space(1))) void*)gsrc,
          (__attribute__((address_space(3))) void*)nb, 16, 0, 0);
      __builtin_amdgcn_global_load_lds(
          (const __attribute__((address_space(1))) void*)(gsrc + 4096),
          (__attribute__((address_space(3))) void*)(nb + 4096), 16, 0, 0);
      gsrc += TB * 256;
    }
    float tv0 = tsq_s[it * TB + lo];
    float tv1 = tsq_s[it * TB + 16 + lo];

    const char* buf = smem + (cur << 13);
    bf16x8 f0[4], f1[4];
#pragma unroll
    for (int kf = 0; kf < 4; ++kf) {
      f0[kf] = *reinterpret_cast<const bf16x8*>(buf + roff[kf]);
      f1[kf] = *reinterpret_cast<const bf16x8*>(buf + roff[kf] + 4096);
    }

    const f32x4 z = {0.f, 0.f, 0.f, 0.f};
    __builtin_amdgcn_s_setprio(1);
#pragma unroll
    for (int t = 0; t < 4; ++t) {
      f32x4 acc0 = __builtin_amdgcn_mfma_f32_16x16x32_bf16(a[t][0], f0[0], z, 0, 0, 0);
      f32x4 acc1 = __builtin_amdgcn_mfma_f32_16x16x32_bf16(a[t][0], f1[0], z, 0, 0, 0);
#pragma unroll
      for (int kf = 1; kf < 4; ++kf) {
        acc0 = __builtin_amdgcn_mfma_f32_16x16x32_bf16(a[t][kf], f0[kf], acc0, 0, 0, 0);
        acc1 = __builtin_amdgcn_mfma_f32_16x16x32_bf16(a[t][kf], f1[kf], acc1, 0, 0, 0);
      }
#pragma unroll
      for (int r = 0; r < 4; ++r) {
        float s0 = fmaf(-2.f, acc0[r], tv0);
        float n1 = fminf(best1[t][r], s0);
        float n2 = __builtin_amdgcn_fmed3f(best1[t][r], best2[t][r], s0);
        best1[t][r] = n1; best2[t][r] = n2;
        float s1 = fmaf(-2.f, acc1[r], tv1);
        n1 = fminf(best1[t][r], s1);
        n2 = __builtin_amdgcn_fmed3f(best1[t][r], best2[t][r], s1);
        best1[t][r] = n1; best2[t][r] = n2;
      }
    }
    __builtin_amdgcn_s_setprio(0);
    __syncthreads();   // drains vmcnt (gll) + lgkmcnt; next tile ready
    cur ^= 1;
  }

  // merge top-2 across the 16 lanes (columns) sharing each query
#pragma unroll
  for (int t = 0; t < 4; ++t)
#pragma unroll
    for (int r = 0; r < 4; ++r) {
      float v1 = best1[t][r], v2 = best2[t][r];
#pragma unroll
      for (int m = 1; m < 16; m <<= 1) {
        float o1 = __shfl_xor(v1, m);
        float o2 = __shfl_xor(v2, m);
        float n1 = fminf(v1, o1);
        float n2 = fminf(fmaxf(v1, o1), fminf(v2, o2));
        v1 = n1;
        v2 = n2;
      }
      best1[t][r] = v1;
      best2[t][r] = v2;
    }
  if (lo == 0) {
#pragma unroll
    for (int t = 0; t < 4; ++t)
#pragma unroll
      for (int r = 0; r < 4; ++r) {
        int q = qw + t * 16 + hi * 4 + r;
        float* p = partials + ((size_t)chunk * M_QUERY + q) * 2;
        p[0] = best1[t][r];
        p[1] = best2[t][r];
      }
  }
}

__global__ __launch_bounds__(256) void knn_reduce(
    const float* __restrict__ partials, const float* __restrict__ qsq,
    float* __restrict__ out, int nchunk) {
  int q = blockIdx.x * 256 + threadIdx.x;
  if (q >= M_QUERY) return;
  const float INF = __builtin_inff();
  float b1 = INF, b2 = INF;
  for (int c = 0; c < nchunk; ++c) {
    const float* p = partials + ((size_t)c * M_QUERY + q) * 2;
    float v = p[0];
    float n1 = fminf(b1, v);
    float n2 = __builtin_amdgcn_fmed3f(b1, b2, v);
    b1 = n1; b2 = n2;
    v = p[1];
    n1 = fminf(b1, v);
    n2 = __builtin_amdgcn_fmed3f(b1, b2, v);
    b1 = n1; b2 = n2;
  }
  out[q] = 2.f * qsq[q] + b1 + b2;
}

extern "C" void kernel_launch(void* const* d_in, const int* in_sizes, int n_in,
                              void* d_out, int out_size, void* d_ws, size_t ws_size,
                              hipStream_t stream) {
  const float* train = (const float*)d_in[0];  // 200000 x 128 f32
  const float* test  = (const float*)d_in[1];  // 2048 x 128 f32
  float* out = (float*)d_out;                  // 2048 f32
  char* ws = (char*)d_ws;

  size_t off_tb  = 0;                                      // train bf16: 51,200,000 B
  size_t off_qb  = off_tb  + (size_t)N_TRAIN * DIMS * 2;   // query bf16
  size_t off_tsq = off_qb  + (size_t)M_QUERY * DIMS * 2;   // t_sq
  size_t off_qsq = off_tsq + (size_t)N_TRAIN * 4;          // q_sq
  size_t off_pt  = off_qsq + (size_t)M_QUERY * 4;          // partials
  size_t need250 = off_pt + (size_t)250 * M_QUERY * 2 * 4;
  size_t need125 = off_pt + (size_t)125 * M_QUERY * 2 * 4;
  if (ws_size < need125) return;
  const bool use250 = (ws_size >= need250);

  unsigned short* tbp = (unsigned short*)(ws + off_tb);
  unsigned short* qb  = (unsigned short*)(ws + off_qb);
  float* tsq = (float*)(ws + off_tsq);
  float* qsq = (float*)(ws + off_qsq);
  float* part = (float*)(ws + off_pt);

  hipLaunchKernelGGL(convert_kernel, dim3((N_TRAIN * 8) / 256), dim3(256), 0, stream,
                     train, tbp, tsq, N_TRAIN);
  hipLaunchKernelGGL(convert_kernel, dim3((M_QUERY * 8) / 256), dim3(256), 0, stream,
                     test, qb, qsq, M_QUERY);
  if (use250) {
    hipLaunchKernelGGL(knn_main<800>, dim3(8, 250), dim3(256), 0, stream,
                       tbp, qb, tsq, part);
    hipLaunchKernelGGL(knn_reduce, dim3(M_QUERY / 256), dim3(256), 0, stream,
                       part, qsq, out, 250);
  } else {
    hipLaunchKernelGGL(knn_main<1600>, dim3(8, 125), dim3(256), 0, stream,
                       tbp, qb, tsq, part);
    hipLaunchKernelGGL(knn_reduce, dim3(M_QUERY / 256), dim3(256), 0, stream,
                       part, qsq, out, 125);
  }
}